// Round 8
// baseline (17979.662 us; speedup 1.0000x reference)
//
#include <hip/hip_runtime.h>
#include <hip/hip_cooperative_groups.h>
#include <stdint.h>

namespace cg = cooperative_groups;

// Skeleton evolution (all PASSing ancestors): R5 per-step f32 anchor -> R6/R7
// per-step MFMA (6.34 ms, launch-overhead-bound) -> R8: same step math, but
// grid-resident cooperative kernel, this_grid().sync() per step (the
// harness-sanctioned device barrier), one launch per 64-step window.
// Persistence wins: W_hh frags in VGPRs once/window; c in register; bf16 xg.

typedef unsigned short u16;
typedef __attribute__((ext_vector_type(8))) short bf16x8;
typedef __attribute__((ext_vector_type(4))) float f32x4;

static __device__ __forceinline__ u16 f2b(float f) {
  uint32_t b = __float_as_uint(f);
  return (u16)((b + 0x7fffu + ((b >> 16) & 1u)) >> 16);  // RNE
}
static __device__ __forceinline__ uint64_t pack4(float4 v) {
  return (uint64_t)f2b(v.x) | ((uint64_t)f2b(v.y) << 16) |
         ((uint64_t)f2b(v.z) << 32) | ((uint64_t)f2b(v.w) << 48);
}
static __device__ __forceinline__ float b2f(u16 u) {
  return __uint_as_float(((uint32_t)u) << 16);
}
static __device__ __forceinline__ float sigm(float x) {
  return 1.0f / (1.0f + __expf(-x));
}
static __device__ __forceinline__ float tanh_(float x) {
  float e = __expf(2.0f * x);
  return 1.0f - 2.0f / (e + 1.0f);
}

// ---------------------------------------------------------------- prep kernels
// W [1024][4096] f32 -> W^T [4096][1024] bf16 (W_ih and W_hh via blockIdx.z)
__global__ __launch_bounds__(256) void transpose_w(const float* __restrict__ Wih,
                                                   const float* __restrict__ Whh,
                                                   u16* __restrict__ Tih,
                                                   u16* __restrict__ Thh) {
  __shared__ float tile[64][65];
  const float* src = blockIdx.z ? Whh : Wih;
  u16* dst = blockIdx.z ? Thh : Tih;
  int k0 = blockIdx.y * 64, n0 = blockIdx.x * 64;
  int tid = threadIdx.x;
#pragma unroll
  for (int i = 0; i < 16; ++i) {
    int idx = i * 256 + tid;
    int kl = idx >> 6, nl = idx & 63;
    tile[kl][nl] = src[(size_t)(k0 + kl) * 4096 + n0 + nl];
  }
  __syncthreads();
#pragma unroll
  for (int i = 0; i < 16; ++i) {
    int idx = i * 256 + tid;
    int nl = idx >> 6, kl = idx & 63;
    dst[(size_t)(n0 + nl) * 1024 + k0 + kl] = f2b(tile[kl][nl]);
  }
}

// h0 [64][1024] f32 -> h_buf[1] bf16
__global__ __launch_bounds__(256) void convert_h0(const float* __restrict__ h0,
                                                  u16* __restrict__ dst) {
  int i = blockIdx.x * 256 + threadIdx.x;  // 16384 float4s
  float4 v = ((const float4*)h0)[i];
  ((uint64_t*)dst)[i] = pack4(v);
}

// ------------------------------------------------------------------- big GEMM
// C[M][4096] bf16 = A[M][1024] f32 @ Bt[4096][1024]^T + bias.  M = gridDim.y*128.
// m97 fragment layout; A and B reg-staged into LDS. (unchanged except bf16 out)
__global__ __launch_bounds__(256) void gemm_xg(const float* __restrict__ A,
                                               const u16* __restrict__ Bt,
                                               const float* __restrict__ bias,
                                               u16* __restrict__ C) {
  __shared__ u16 sA[2][128 * 32];
  __shared__ u16 sB[2][128 * 32];
  const int tid = threadIdx.x;
  const int wave = tid >> 6, lane = tid & 63;
  const int bx = blockIdx.x, by = blockIdx.y;
  const int wr = wave >> 1, wc = wave & 1;  // wave computes 64x64
  const int lm = lane & 15, ko = (lane >> 4) * 8;

  const int ar = lane >> 1, ac = (lane & 1) * 16;
  const float* gA = A + (size_t)(by * 128 + wave * 32 + ar) * 1024 + ac;
  const u16* gB = Bt + (size_t)(bx * 128 + wave * 32 + (lane >> 2)) * 1024 + (lane & 3) * 8;
  const int bidx = wave * 1024 + (lane >> 2) * 32 + (lane & 3) * 8;

  f32x4 acc[4][4] = {};

  auto stage = [&](int kt, int buf) {
    const u16* gb = gB + kt * 32;
    bf16x8 b0 = *(const bf16x8*)gb;
    bf16x8 b1 = *(const bf16x8*)(gb + 16 * 1024);
    *(bf16x8*)&sB[buf][bidx] = b0;
    *(bf16x8*)&sB[buf][bidx + 512] = b1;
    const float* ga = gA + kt * 32;
    float4 v0 = *(const float4*)(ga + 0);
    float4 v1 = *(const float4*)(ga + 4);
    float4 v2 = *(const float4*)(ga + 8);
    float4 v3 = *(const float4*)(ga + 12);
    uint64_t* la = (uint64_t*)&sA[buf][wave * 1024 + ar * 32 + ac];
    la[0] = pack4(v0);
    la[1] = pack4(v1);
    la[2] = pack4(v2);
    la[3] = pack4(v3);
  };

  stage(0, 0);
  __syncthreads();
  int p = 0;
  for (int kt = 0; kt < 32; ++kt) {
    if (kt < 31) stage(kt + 1, p ^ 1);
    bf16x8 af[4], bfv[4];
#pragma unroll
    for (int i = 0; i < 4; ++i)
      af[i] = *(const bf16x8*)&sA[p][(wr * 64 + i * 16 + lm) * 32 + ko];
#pragma unroll
    for (int j = 0; j < 4; ++j)
      bfv[j] = *(const bf16x8*)&sB[p][(wc * 64 + j * 16 + lm) * 32 + ko];
#pragma unroll
    for (int i = 0; i < 4; ++i)
#pragma unroll
      for (int j = 0; j < 4; ++j)
        acc[i][j] = __builtin_amdgcn_mfma_f32_16x16x32_bf16(af[i], bfv[j], acc[i][j], 0, 0, 0);
    __syncthreads();
    p ^= 1;
  }

  float bj[4];
#pragma unroll
  for (int j = 0; j < 4; ++j)
    bj[j] = bias[bx * 128 + wc * 64 + j * 16 + lm];
#pragma unroll
  for (int i = 0; i < 4; ++i) {
    int row = by * 128 + wr * 64 + i * 16 + (lane >> 4) * 4;
#pragma unroll
    for (int j = 0; j < 4; ++j) {
      int col = bx * 128 + wc * 64 + j * 16 + lm;
#pragma unroll
      for (int r = 0; r < 4; ++r)
        C[(size_t)(row + r) * 4096 + col] = f2b(acc[i][j][r] + bj[j]);
    }
  }
}

// -------------------------------------------- cooperative window recurrence
// One launch per W-step window. Grid 256 blocks (1/CU), block 512 (8 waves).
// Block bid: ub=bid&63 (units ub*16..+16), bq=bid>>6 (batch rows bq*16..+16).
// Wave w=(gate=w&3, kh=w>>2): 16x16 gate tile over K-half kh as two 8-deep
// MFMA chains; B-frags resident in VGPRs for the whole window.
// Step math identical to round 7 (PASS); only the barrier is grid.sync().
__global__ __launch_bounds__(512, 1) void recur_coop(
    const u16* __restrict__ xg,      // [W][64][4096] bf16, bias already added
    const u16* __restrict__ whh_t,   // [4096][1024] bf16
    u16* __restrict__ h_buf,         // [2][64][1024] bf16 ping-pong
    float* __restrict__ c_st,        // [64][1024] f32
    float* __restrict__ out_h,       // [512][64][1024] f32
    float* __restrict__ out_hT, float* __restrict__ out_cT,
    int t0, int W) {
  cg::grid_group grid = cg::this_grid();
  __shared__ float xchg[8][16][16];

  const int tid = threadIdx.x;
  const int wave = tid >> 6, lane = tid & 63;
  const int gate = wave & 3, kh = wave >> 2;
  const int bid = blockIdx.x;
  const int ub = bid & 63;
  const int bq = bid >> 6;
  const int lm = lane & 15, ko = (lane >> 4) * 8;

  // ---- W_hh B-frags resident for the window: 16 x bf16x8 = 64 VGPRs ----
  bf16x8 bfr[16];
  {
    const u16* bp = whh_t + (size_t)(gate * 1024 + ub * 16 + lm) * 1024 + kh * 512 + ko;
#pragma unroll
    for (int kk = 0; kk < 16; ++kk) bfr[kk] = *(const bf16x8*)(bp + kk * 32);
  }

  // ---- epilogue ownership: tid<256 -> (b, unit); c in register ----
  const int r_b = tid >> 4, u = tid & 15;
  const int b = bq * 16 + r_b;
  const int unit = ub * 16 + u;
  float c_val = (tid < 256) ? c_st[b * 1024 + unit] : 0.f;

  for (int ts = 0; ts < W; ++ts) {
    const int t = t0 + ts;

    // xg prefetch (independent of h; overlaps the A-load + MFMA chain)
    u16 xr0 = 0, xr1 = 0, xr2 = 0, xr3 = 0;
    if (tid < 256) {
      const u16* xgp = xg + ((size_t)ts * 64 + b) * 4096 + unit;
      xr0 = xgp[0];
      xr1 = xgp[1024];
      xr2 = xgp[2048];
      xr3 = xgp[3072];
    }

    const u16* ap =
        h_buf + (size_t)((t - 1) & 1) * 65536 + (size_t)(bq * 16 + lm) * 1024 + kh * 512 + ko;
    f32x4 acc0 = {0.f, 0.f, 0.f, 0.f}, acc1 = acc0;
#pragma unroll
    for (int kk = 0; kk < 8; ++kk) {
      bf16x8 a0 = *(const bf16x8*)(ap + (2 * kk) * 32);
      bf16x8 a1 = *(const bf16x8*)(ap + (2 * kk + 1) * 32);
      acc0 = __builtin_amdgcn_mfma_f32_16x16x32_bf16(a0, bfr[2 * kk], acc0, 0, 0, 0);
      acc1 = __builtin_amdgcn_mfma_f32_16x16x32_bf16(a1, bfr[2 * kk + 1], acc1, 0, 0, 0);
    }
    f32x4 acc = acc0 + acc1;
    {
      int crow = (lane >> 4) * 4;  // C layout: col=lane&15, row=(lane>>4)*4+r
#pragma unroll
      for (int r = 0; r < 4; ++r) xchg[wave][crow + r][lm] = acc[r];
    }
    __syncthreads();

    if (tid < 256) {
      float r0 = xchg[0][r_b][u] + xchg[4][r_b][u] + b2f(xr0);
      float r1 = xchg[1][r_b][u] + xchg[5][r_b][u] + b2f(xr1);
      float r2 = xchg[2][r_b][u] + xchg[6][r_b][u] + b2f(xr2);
      float r3 = xchg[3][r_b][u] + xchg[7][r_b][u] + b2f(xr3);
      float ig = sigm(r0), fg = sigm(r1), gg = tanh_(r2), og = sigm(r3);
      c_val = fg * c_val + ig * gg;
      float h_new = og * tanh_(c_val);
      h_buf[(size_t)(t & 1) * 65536 + (size_t)b * 1024 + unit] = f2b(h_new);
      out_h[(size_t)t * 65536 + (size_t)b * 1024 + unit] = h_new;
      if (t == 511) {
        out_hT[b * 1024 + unit] = h_new;
        out_cT[b * 1024 + unit] = c_val;
      }
    }

    if (ts != W - 1) grid.sync();  // device barrier: h_buf visible, xchg safe
  }

  if (tid < 256) c_st[b * 1024 + unit] = c_val;
}

// -------------------------------------------------------------------- launch
extern "C" void kernel_launch(void* const* d_in, const int* in_sizes, int n_in,
                              void* d_out, int out_size, void* d_ws, size_t ws_size,
                              hipStream_t stream) {
  const float* x = (const float*)d_in[0];
  const float* h0 = (const float*)d_in[1];
  const float* c0 = (const float*)d_in[2];
  const float* wih = (const float*)d_in[3];
  const float* whh = (const float*)d_in[4];
  const float* bias = (const float*)d_in[5];

  float* out = (float*)d_out;
  float* out_h = out;                              // [512][64][1024]
  float* out_hT = out + (size_t)512 * 64 * 1024;   // [64][1024]
  float* out_cT = out_hT + 64 * 1024;              // [64][1024]

  // adaptive xg window (bf16): W in {64,16,4}
  const size_t fixed = (size_t)2 * 4096 * 1024 * 2   // wih_t + whh_t
                       + (size_t)2 * 64 * 1024 * 2   // h_buf bf16 ping-pong
                       + (size_t)64 * 1024 * 4;      // c_state
  int W = 64;
  while (W > 4 && fixed + (size_t)W * 64 * 4096 * 2 > ws_size) W >>= 2;

  char* ws = (char*)d_ws;
  u16* wih_t = (u16*)ws;   ws += (size_t)4096 * 1024 * 2;    // 8MB
  u16* whh_t = (u16*)ws;   ws += (size_t)4096 * 1024 * 2;    // 8MB
  u16* xg = (u16*)ws;      ws += (size_t)W * 64 * 4096 * 2;  // <=32MB
  u16* h_buf = (u16*)ws;   ws += (size_t)2 * 64 * 1024 * 2;  // 256KB
  float* c_st = (float*)ws;                                  // 256KB

  convert_h0<<<64, 256, 0, stream>>>(h0, h_buf + 65536);  // h_{-1} in buf 1
  hipMemcpyAsync(c_st, c0, (size_t)64 * 1024 * 4, hipMemcpyDeviceToDevice, stream);
  transpose_w<<<dim3(64, 16, 2), 256, 0, stream>>>(wih, whh, wih_t, whh_t);

  for (int t0 = 0; t0 < 512; t0 += W) {
    gemm_xg<<<dim3(32, W / 2), 256, 0, stream>>>(x + (size_t)t0 * 64 * 1024, wih_t, bias, xg);
    int t0c = t0, Wc = W;
    void* args[] = {(void*)&xg,    (void*)&whh_t,  (void*)&h_buf,
                    (void*)&c_st,  (void*)&out_h,  (void*)&out_hT,
                    (void*)&out_cT, (void*)&t0c,   (void*)&Wc};
    hipLaunchCooperativeKernel((const void*)recur_coop, dim3(256), dim3(512), args, 0,
                               stream);
  }
}

// Round 9
// 6352.898 us; speedup vs baseline: 2.8302x; 2.8302x over previous
//
#include <hip/hip_runtime.h>
#include <stdint.h>

// R9: round-8 structure (PASS), but grid.sync() (34µs/step, 98% idle per
// rocprof) replaced by a fence-free per-(step,bq) counter barrier:
//  - batch-groups are independent: block (ub,bq) only touches batch rows
//    bq*16..+16  => barrier over 64 blocks, not 256.
//  - h_buf stores/loads are agent-scope relaxed atomics (sc-bits -> L3
//    coherence point, bypassing non-coherent per-XCD L2s).
//  - __syncthreads() drains vmcnt(0) before the arrive => write-through
//    stores already globally visible; no threadfence / L2 writeback needed.
//  - bounded spin + 1e6 sentinel: can never wedge the GPU.
// (Rounds 2-4's persistent-kernel failures root-caused to a half-sized LDS
// staging loop, not the barrier protocol; this kernel stages nothing to LDS.)

typedef unsigned short u16;
typedef __attribute__((ext_vector_type(8))) short bf16x8;
typedef __attribute__((ext_vector_type(2))) uint64_t u64x2;
typedef __attribute__((ext_vector_type(4))) float f32x4;

static __device__ __forceinline__ u16 f2b(float f) {
  uint32_t b = __float_as_uint(f);
  return (u16)((b + 0x7fffu + ((b >> 16) & 1u)) >> 16);  // RNE
}
static __device__ __forceinline__ uint64_t pack4(float4 v) {
  return (uint64_t)f2b(v.x) | ((uint64_t)f2b(v.y) << 16) |
         ((uint64_t)f2b(v.z) << 32) | ((uint64_t)f2b(v.w) << 48);
}
static __device__ __forceinline__ float b2f(u16 u) {
  return __uint_as_float(((uint32_t)u) << 16);
}
static __device__ __forceinline__ float sigm(float x) {
  return 1.0f / (1.0f + __expf(-x));
}
static __device__ __forceinline__ float tanh_(float x) {
  float e = __expf(2.0f * x);
  return 1.0f - 2.0f / (e + 1.0f);
}

// ---------------------------------------------------------------- prep kernels
__global__ __launch_bounds__(256) void transpose_w(const float* __restrict__ Wih,
                                                   const float* __restrict__ Whh,
                                                   u16* __restrict__ Tih,
                                                   u16* __restrict__ Thh) {
  __shared__ float tile[64][65];
  const float* src = blockIdx.z ? Whh : Wih;
  u16* dst = blockIdx.z ? Thh : Tih;
  int k0 = blockIdx.y * 64, n0 = blockIdx.x * 64;
  int tid = threadIdx.x;
#pragma unroll
  for (int i = 0; i < 16; ++i) {
    int idx = i * 256 + tid;
    int kl = idx >> 6, nl = idx & 63;
    tile[kl][nl] = src[(size_t)(k0 + kl) * 4096 + n0 + nl];
  }
  __syncthreads();
#pragma unroll
  for (int i = 0; i < 16; ++i) {
    int idx = i * 256 + tid;
    int nl = idx >> 6, kl = idx & 63;
    dst[(size_t)(n0 + nl) * 1024 + k0 + kl] = f2b(tile[kl][nl]);
  }
}

__global__ __launch_bounds__(256) void convert_h0(const float* __restrict__ h0,
                                                  u16* __restrict__ dst) {
  int i = blockIdx.x * 256 + threadIdx.x;  // 16384 float4s
  float4 v = ((const float4*)h0)[i];
  ((uint64_t*)dst)[i] = pack4(v);
}

// ------------------------------------------------------------------- big GEMM
// C[M][4096] bf16 = A[M][1024] f32 @ Bt[4096][1024]^T + bias. (round-8, PASS)
__global__ __launch_bounds__(256) void gemm_xg(const float* __restrict__ A,
                                               const u16* __restrict__ Bt,
                                               const float* __restrict__ bias,
                                               u16* __restrict__ C) {
  __shared__ u16 sA[2][128 * 32];
  __shared__ u16 sB[2][128 * 32];
  const int tid = threadIdx.x;
  const int wave = tid >> 6, lane = tid & 63;
  const int bx = blockIdx.x, by = blockIdx.y;
  const int wr = wave >> 1, wc = wave & 1;
  const int lm = lane & 15, ko = (lane >> 4) * 8;

  const int ar = lane >> 1, ac = (lane & 1) * 16;
  const float* gA = A + (size_t)(by * 128 + wave * 32 + ar) * 1024 + ac;
  const u16* gB = Bt + (size_t)(bx * 128 + wave * 32 + (lane >> 2)) * 1024 + (lane & 3) * 8;
  const int bidx = wave * 1024 + (lane >> 2) * 32 + (lane & 3) * 8;

  f32x4 acc[4][4] = {};

  auto stage = [&](int kt, int buf) {
    const u16* gb = gB + kt * 32;
    bf16x8 b0 = *(const bf16x8*)gb;
    bf16x8 b1 = *(const bf16x8*)(gb + 16 * 1024);
    *(bf16x8*)&sB[buf][bidx] = b0;
    *(bf16x8*)&sB[buf][bidx + 512] = b1;
    const float* ga = gA + kt * 32;
    float4 v0 = *(const float4*)(ga + 0);
    float4 v1 = *(const float4*)(ga + 4);
    float4 v2 = *(const float4*)(ga + 8);
    float4 v3 = *(const float4*)(ga + 12);
    uint64_t* la = (uint64_t*)&sA[buf][wave * 1024 + ar * 32 + ac];
    la[0] = pack4(v0);
    la[1] = pack4(v1);
    la[2] = pack4(v2);
    la[3] = pack4(v3);
  };

  stage(0, 0);
  __syncthreads();
  int p = 0;
  for (int kt = 0; kt < 32; ++kt) {
    if (kt < 31) stage(kt + 1, p ^ 1);
    bf16x8 af[4], bfv[4];
#pragma unroll
    for (int i = 0; i < 4; ++i)
      af[i] = *(const bf16x8*)&sA[p][(wr * 64 + i * 16 + lm) * 32 + ko];
#pragma unroll
    for (int j = 0; j < 4; ++j)
      bfv[j] = *(const bf16x8*)&sB[p][(wc * 64 + j * 16 + lm) * 32 + ko];
#pragma unroll
    for (int i = 0; i < 4; ++i)
#pragma unroll
      for (int j = 0; j < 4; ++j)
        acc[i][j] = __builtin_amdgcn_mfma_f32_16x16x32_bf16(af[i], bfv[j], acc[i][j], 0, 0, 0);
    __syncthreads();
    p ^= 1;
  }

  float bj[4];
#pragma unroll
  for (int j = 0; j < 4; ++j)
    bj[j] = bias[bx * 128 + wc * 64 + j * 16 + lm];
#pragma unroll
  for (int i = 0; i < 4; ++i) {
    int row = by * 128 + wr * 64 + i * 16 + (lane >> 4) * 4;
#pragma unroll
    for (int j = 0; j < 4; ++j) {
      int col = bx * 128 + wc * 64 + j * 16 + lm;
#pragma unroll
      for (int r = 0; r < 4; ++r)
        C[(size_t)(row + r) * 4096 + col] = f2b(acc[i][j][r] + bj[j]);
    }
  }
}

// -------------------------------------------- persistent window recurrence
// Grid 256 blocks, block 512 (8 waves). bid: ub=bid&63, bq=bid>>6.
// Wave w=(gate=w&3, kh=w>>2). Step math identical to rounds 7/8 (PASS).
// Per-step barrier: 64-block (same-bq) counter, fence-free (see header).
__global__ __launch_bounds__(512, 1) void recur_pers(
    const u16* __restrict__ xg,      // [W][64][4096] bf16, bias already added
    const u16* __restrict__ whh_t,   // [4096][1024] bf16
    u16* __restrict__ h_buf,         // [2][64][1024] bf16 ping-pong
    float* __restrict__ c_st,        // [64][1024] f32
    float* __restrict__ out_h,       // [512][64][1024] f32
    float* __restrict__ out_hT, float* __restrict__ out_cT,
    uint32_t* __restrict__ cnt,      // [512][4] counters, 64B-strided
    int t0, int W) {
  __shared__ float xchg[8][16][16];

  const int tid = threadIdx.x;
  const int wave = tid >> 6, lane = tid & 63;
  const int gate = wave & 3, kh = wave >> 2;
  const int bid = blockIdx.x;
  const int ub = bid & 63;
  const int bq = bid >> 6;
  const int lm = lane & 15, ko = (lane >> 4) * 8;

  // W_hh B-frags resident for the window (64 VGPRs)
  bf16x8 bfr[16];
  {
    const u16* bp = whh_t + (size_t)(gate * 1024 + ub * 16 + lm) * 1024 + kh * 512 + ko;
#pragma unroll
    for (int kk = 0; kk < 16; ++kk) bfr[kk] = *(const bf16x8*)(bp + kk * 32);
  }

  const int r_b = tid >> 4, u = tid & 15;
  const int b = bq * 16 + r_b;
  const int unit = ub * 16 + u;
  float c_val = (tid < 256) ? c_st[b * 1024 + unit] : 0.f;

  for (int ts = 0; ts < W; ++ts) {
    const int t = t0 + ts;

    // xg prefetch (independent of h; plain cached loads)
    u16 xr0 = 0, xr1 = 0, xr2 = 0, xr3 = 0;
    if (tid < 256) {
      const u16* xgp = xg + ((size_t)ts * 64 + b) * 4096 + unit;
      xr0 = xgp[0];
      xr1 = xgp[1024];
      xr2 = xgp[2048];
      xr3 = xgp[3072];
    }

    // A-frags: agent-scope atomic loads (bypass non-coherent L1/L2 -> L3)
    const u16* ap =
        h_buf + (size_t)((t - 1) & 1) * 65536 + (size_t)(bq * 16 + lm) * 1024 + kh * 512 + ko;
    f32x4 acc0 = {0.f, 0.f, 0.f, 0.f}, acc1 = acc0;
#pragma unroll
    for (int kk = 0; kk < 8; ++kk) {
      const uint64_t* p0 = (const uint64_t*)(ap + (2 * kk) * 32);
      const uint64_t* p1 = (const uint64_t*)(ap + (2 * kk + 1) * 32);
      u64x2 va, vb;
      va.x = __hip_atomic_load(p0, __ATOMIC_RELAXED, __HIP_MEMORY_SCOPE_AGENT);
      va.y = __hip_atomic_load(p0 + 1, __ATOMIC_RELAXED, __HIP_MEMORY_SCOPE_AGENT);
      vb.x = __hip_atomic_load(p1, __ATOMIC_RELAXED, __HIP_MEMORY_SCOPE_AGENT);
      vb.y = __hip_atomic_load(p1 + 1, __ATOMIC_RELAXED, __HIP_MEMORY_SCOPE_AGENT);
      bf16x8 a0 = __builtin_bit_cast(bf16x8, va);
      bf16x8 a1 = __builtin_bit_cast(bf16x8, vb);
      acc0 = __builtin_amdgcn_mfma_f32_16x16x32_bf16(a0, bfr[2 * kk], acc0, 0, 0, 0);
      acc1 = __builtin_amdgcn_mfma_f32_16x16x32_bf16(a1, bfr[2 * kk + 1], acc1, 0, 0, 0);
    }
    f32x4 acc = acc0 + acc1;
    {
      int crow = (lane >> 4) * 4;  // C layout: col=lane&15, row=(lane>>4)*4+r
#pragma unroll
      for (int r = 0; r < 4; ++r) xchg[wave][crow + r][lm] = acc[r];
    }
    __syncthreads();

    if (tid < 256) {
      float r0 = xchg[0][r_b][u] + xchg[4][r_b][u] + b2f(xr0);
      float r1 = xchg[1][r_b][u] + xchg[5][r_b][u] + b2f(xr1);
      float r2 = xchg[2][r_b][u] + xchg[6][r_b][u] + b2f(xr2);
      float r3 = xchg[3][r_b][u] + xchg[7][r_b][u] + b2f(xr3);
      float ig = sigm(r0), fg = sigm(r1), gg = tanh_(r2), og = sigm(r3);
      c_val = fg * c_val + ig * gg;
      float h_new = og * tanh_(c_val);
      // paired u32 agent-scope store (write-through to coherence point)
      uint32_t mine = f2b(h_new);
      uint32_t other = __shfl_xor(mine, 1);
      if ((u & 1) == 0) {
        uint32_t pair = mine | (other << 16);
        __hip_atomic_store(
            (uint32_t*)(h_buf + (size_t)(t & 1) * 65536 + (size_t)b * 1024 + unit), pair,
            __ATOMIC_RELAXED, __HIP_MEMORY_SCOPE_AGENT);
      }
      out_h[(size_t)t * 65536 + (size_t)b * 1024 + unit] = h_new;
      if (t == 511) {
        out_hT[b * 1024 + unit] = h_new;
        out_cT[b * 1024 + unit] = c_val;
      }
    }

    // fence-free 64-block barrier over the bq group
    if (ts != W - 1) {
      __syncthreads();  // drains vmcnt(0): h stores are at L3 before arrive
      if (tid == 0) {
        uint32_t* c = cnt + ((size_t)t * 4 + bq) * 16;  // 64B-strided counter
        __hip_atomic_fetch_add(c, 1u, __ATOMIC_RELAXED, __HIP_MEMORY_SCOPE_AGENT);
        uint32_t spin = 0;
        for (; spin < (1u << 15); ++spin) {
          if (__hip_atomic_load(c, __ATOMIC_RELAXED, __HIP_MEMORY_SCOPE_AGENT) >= 64u)
            break;
          __builtin_amdgcn_s_sleep(1);
        }
        if (spin >= (1u << 15))  // sentinel: absmax ~1e6 => barrier timeout
          out_h[(size_t)t * 65536 + bid] = 1.0e6f;
      }
      __syncthreads();
    }
  }

  if (tid < 256) c_st[b * 1024 + unit] = c_val;
}

// -------------------------------------------------------------------- launch
extern "C" void kernel_launch(void* const* d_in, const int* in_sizes, int n_in,
                              void* d_out, int out_size, void* d_ws, size_t ws_size,
                              hipStream_t stream) {
  const float* x = (const float*)d_in[0];
  const float* h0 = (const float*)d_in[1];
  const float* c0 = (const float*)d_in[2];
  const float* wih = (const float*)d_in[3];
  const float* whh = (const float*)d_in[4];
  const float* bias = (const float*)d_in[5];

  float* out = (float*)d_out;
  float* out_h = out;                              // [512][64][1024]
  float* out_hT = out + (size_t)512 * 64 * 1024;   // [64][1024]
  float* out_cT = out_hT + 64 * 1024;              // [64][1024]

  // adaptive xg window (bf16): W in {64,16,4}
  const size_t fixed = (size_t)2 * 4096 * 1024 * 2   // wih_t + whh_t
                       + (size_t)2 * 64 * 1024 * 2   // h_buf
                       + (size_t)64 * 1024 * 4       // c_state
                       + (size_t)512 * 4 * 64;       // counters
  int W = 64;
  while (W > 4 && fixed + (size_t)W * 64 * 4096 * 2 > ws_size) W >>= 2;

  char* ws = (char*)d_ws;
  u16* wih_t = (u16*)ws;   ws += (size_t)4096 * 1024 * 2;    // 8MB
  u16* whh_t = (u16*)ws;   ws += (size_t)4096 * 1024 * 2;    // 8MB
  u16* xg = (u16*)ws;      ws += (size_t)W * 64 * 4096 * 2;  // <=32MB
  u16* h_buf = (u16*)ws;   ws += (size_t)2 * 64 * 1024 * 2;  // 256KB
  float* c_st = (float*)ws; ws += (size_t)64 * 1024 * 4;     // 256KB
  uint32_t* cnt = (uint32_t*)ws;                             // 128KB

  hipMemsetAsync(cnt, 0, (size_t)512 * 4 * 64, stream);
  convert_h0<<<64, 256, 0, stream>>>(h0, h_buf + 65536);  // h_{-1} in buf 1
  hipMemcpyAsync(c_st, c0, (size_t)64 * 1024 * 4, hipMemcpyDeviceToDevice, stream);
  transpose_w<<<dim3(64, 16, 2), 256, 0, stream>>>(wih, whh, wih_t, whh_t);

  for (int t0 = 0; t0 < 512; t0 += W) {
    gemm_xg<<<dim3(32, W / 2), 256, 0, stream>>>(x + (size_t)t0 * 64 * 1024, wih_t, bias, xg);
    int t0c = t0, Wc = W;
    void* args[] = {(void*)&xg,     (void*)&whh_t, (void*)&h_buf, (void*)&c_st,
                    (void*)&out_h,  (void*)&out_hT, (void*)&out_cT, (void*)&cnt,
                    (void*)&t0c,    (void*)&Wc};
    hipLaunchCooperativeKernel((const void*)recur_pers, dim3(256), dim3(512), args, 0,
                               stream);
  }
}

// Round 10
// 4222.363 us; speedup vs baseline: 4.2582x; 1.5046x over previous
//
#include <hip/hip_runtime.h>
#include <stdint.h>

// R10: R9 structure (PASS) with the barrier critical path rebuilt:
//  (1) arrival = per-block flag STORE (no serialized fetch_add chain);
//      detection = wave 7 polling 64 flags via one coalesced load/lane + __all.
//  (2) out_h stores moved after the arrive (overlap the poll, not the drain).
//  (3) wave = K-slice(128) x all-4-gates (was (gate,K-half)): 4x less
//      redundant agent-scope h traffic, 4 independent MFMA chains.
// Protocol invariant (R9-proven): h_buf agent-scope stores -> __syncthreads
// (vmcnt drain => globally visible) -> flag store -> poll -> read h agent-scope.

typedef unsigned short u16;
typedef __attribute__((ext_vector_type(8))) short bf16x8;
typedef __attribute__((ext_vector_type(2))) uint64_t u64x2;
typedef __attribute__((ext_vector_type(4))) float f32x4;

static __device__ __forceinline__ u16 f2b(float f) {
  uint32_t b = __float_as_uint(f);
  return (u16)((b + 0x7fffu + ((b >> 16) & 1u)) >> 16);  // RNE
}
static __device__ __forceinline__ uint64_t pack4(float4 v) {
  return (uint64_t)f2b(v.x) | ((uint64_t)f2b(v.y) << 16) |
         ((uint64_t)f2b(v.z) << 32) | ((uint64_t)f2b(v.w) << 48);
}
static __device__ __forceinline__ float b2f(u16 u) {
  return __uint_as_float(((uint32_t)u) << 16);
}
static __device__ __forceinline__ float sigm(float x) {
  return 1.0f / (1.0f + __expf(-x));
}
static __device__ __forceinline__ float tanh_(float x) {
  float e = __expf(2.0f * x);
  return 1.0f - 2.0f / (e + 1.0f);
}

// ---------------------------------------------------------------- prep kernels
__global__ __launch_bounds__(256) void transpose_w(const float* __restrict__ Wih,
                                                   const float* __restrict__ Whh,
                                                   u16* __restrict__ Tih,
                                                   u16* __restrict__ Thh) {
  __shared__ float tile[64][65];
  const float* src = blockIdx.z ? Whh : Wih;
  u16* dst = blockIdx.z ? Thh : Tih;
  int k0 = blockIdx.y * 64, n0 = blockIdx.x * 64;
  int tid = threadIdx.x;
#pragma unroll
  for (int i = 0; i < 16; ++i) {
    int idx = i * 256 + tid;
    int kl = idx >> 6, nl = idx & 63;
    tile[kl][nl] = src[(size_t)(k0 + kl) * 4096 + n0 + nl];
  }
  __syncthreads();
#pragma unroll
  for (int i = 0; i < 16; ++i) {
    int idx = i * 256 + tid;
    int nl = idx >> 6, kl = idx & 63;
    dst[(size_t)(n0 + nl) * 1024 + k0 + kl] = f2b(tile[kl][nl]);
  }
}

__global__ __launch_bounds__(256) void convert_h0(const float* __restrict__ h0,
                                                  u16* __restrict__ dst) {
  int i = blockIdx.x * 256 + threadIdx.x;  // 16384 float4s
  float4 v = ((const float4*)h0)[i];
  ((uint64_t*)dst)[i] = pack4(v);
}

// ------------------------------------------------------------------- big GEMM
// C[M][4096] bf16 = A[M][1024] f32 @ Bt[4096][1024]^T + bias. (unchanged, PASS)
__global__ __launch_bounds__(256) void gemm_xg(const float* __restrict__ A,
                                               const u16* __restrict__ Bt,
                                               const float* __restrict__ bias,
                                               u16* __restrict__ C) {
  __shared__ u16 sA[2][128 * 32];
  __shared__ u16 sB[2][128 * 32];
  const int tid = threadIdx.x;
  const int wave = tid >> 6, lane = tid & 63;
  const int bx = blockIdx.x, by = blockIdx.y;
  const int wr = wave >> 1, wc = wave & 1;
  const int lm = lane & 15, ko = (lane >> 4) * 8;

  const int ar = lane >> 1, ac = (lane & 1) * 16;
  const float* gA = A + (size_t)(by * 128 + wave * 32 + ar) * 1024 + ac;
  const u16* gB = Bt + (size_t)(bx * 128 + wave * 32 + (lane >> 2)) * 1024 + (lane & 3) * 8;
  const int bidx = wave * 1024 + (lane >> 2) * 32 + (lane & 3) * 8;

  f32x4 acc[4][4] = {};

  auto stage = [&](int kt, int buf) {
    const u16* gb = gB + kt * 32;
    bf16x8 b0 = *(const bf16x8*)gb;
    bf16x8 b1 = *(const bf16x8*)(gb + 16 * 1024);
    *(bf16x8*)&sB[buf][bidx] = b0;
    *(bf16x8*)&sB[buf][bidx + 512] = b1;
    const float* ga = gA + kt * 32;
    float4 v0 = *(const float4*)(ga + 0);
    float4 v1 = *(const float4*)(ga + 4);
    float4 v2 = *(const float4*)(ga + 8);
    float4 v3 = *(const float4*)(ga + 12);
    uint64_t* la = (uint64_t*)&sA[buf][wave * 1024 + ar * 32 + ac];
    la[0] = pack4(v0);
    la[1] = pack4(v1);
    la[2] = pack4(v2);
    la[3] = pack4(v3);
  };

  stage(0, 0);
  __syncthreads();
  int p = 0;
  for (int kt = 0; kt < 32; ++kt) {
    if (kt < 31) stage(kt + 1, p ^ 1);
    bf16x8 af[4], bfv[4];
#pragma unroll
    for (int i = 0; i < 4; ++i)
      af[i] = *(const bf16x8*)&sA[p][(wr * 64 + i * 16 + lm) * 32 + ko];
#pragma unroll
    for (int j = 0; j < 4; ++j)
      bfv[j] = *(const bf16x8*)&sB[p][(wc * 64 + j * 16 + lm) * 32 + ko];
#pragma unroll
    for (int i = 0; i < 4; ++i)
#pragma unroll
      for (int j = 0; j < 4; ++j)
        acc[i][j] = __builtin_amdgcn_mfma_f32_16x16x32_bf16(af[i], bfv[j], acc[i][j], 0, 0, 0);
    __syncthreads();
    p ^= 1;
  }

  float bj[4];
#pragma unroll
  for (int j = 0; j < 4; ++j)
    bj[j] = bias[bx * 128 + wc * 64 + j * 16 + lm];
#pragma unroll
  for (int i = 0; i < 4; ++i) {
    int row = by * 128 + wr * 64 + i * 16 + (lane >> 4) * 4;
#pragma unroll
    for (int j = 0; j < 4; ++j) {
      int col = bx * 128 + wc * 64 + j * 16 + lm;
#pragma unroll
      for (int r = 0; r < 4; ++r)
        C[(size_t)(row + r) * 4096 + col] = f2b(acc[i][j][r] + bj[j]);
    }
  }
}

// -------------------------------------------- persistent window recurrence
// Grid 256 blocks, block 512 (8 waves). bid: ub=bid&63, bq=bid>>6.
// Wave w owns K-slice [w*128, w*128+128) for ALL 4 gates: bfr[gate][kc]
// resident (64 VGPRs); per step 4 A-frags (16B/lane, agent-scope) feed 4
// independent 4-deep MFMA chains. 32KB xchg reduce (2-way banks = free).
__global__ __launch_bounds__(512, 1) void recur_pers(
    const u16* __restrict__ xg,      // [W][64][4096] bf16, bias already added
    const u16* __restrict__ whh_t,   // [4096][1024] bf16
    u16* __restrict__ h_buf,         // [2][64][1024] bf16 ping-pong
    float* __restrict__ c_st,        // [64][1024] f32
    float* __restrict__ out_h,       // [512][64][1024] f32
    float* __restrict__ out_hT, float* __restrict__ out_cT,
    uint32_t* __restrict__ flags,    // [512][4][64] u32, zeroed per launch
    int t0, int W) {
  __shared__ float xchg[8][4][16][16];  // 32KB

  const int tid = threadIdx.x;
  const int wave = tid >> 6, lane = tid & 63;
  const int bid = blockIdx.x;
  const int ub = bid & 63;
  const int bq = bid >> 6;
  const int lm = lane & 15, ko = (lane >> 4) * 8;

  // W_hh B-frags resident: bfr[gate][kc], k = wave*128 + kc*32 + ko + j
  bf16x8 bfr[4][4];
#pragma unroll
  for (int g = 0; g < 4; ++g) {
    const u16* bp = whh_t + (size_t)(g * 1024 + ub * 16 + lm) * 1024 + wave * 128 + ko;
#pragma unroll
    for (int kc = 0; kc < 4; ++kc) bfr[g][kc] = *(const bf16x8*)(bp + kc * 32);
  }

  const int r_b = tid >> 4, u = tid & 15;
  const int b = bq * 16 + r_b;
  const int unit = ub * 16 + u;
  float c_val = (tid < 256) ? c_st[b * 1024 + unit] : 0.f;

  for (int ts = 0; ts < W; ++ts) {
    const int t = t0 + ts;

    // xg prefetch (independent of h; overlaps the h-load + MFMA)
    u16 xr0 = 0, xr1 = 0, xr2 = 0, xr3 = 0;
    if (tid < 256) {
      const u16* xgp = xg + ((size_t)ts * 64 + b) * 4096 + unit;
      xr0 = xgp[0];
      xr1 = xgp[1024];
      xr2 = xgp[2048];
      xr3 = xgp[3072];
    }

    // A-frags: 4 x 16B per lane, agent-scope (L3 coherence point)
    const u16* ap = h_buf + (size_t)((t - 1) & 1) * 65536 +
                    (size_t)(bq * 16 + lm) * 1024 + wave * 128 + ko;
    bf16x8 a[4];
#pragma unroll
    for (int kc = 0; kc < 4; ++kc) {
      const uint64_t* p = (const uint64_t*)(ap + kc * 32);
      u64x2 v;
      v.x = __hip_atomic_load(p, __ATOMIC_RELAXED, __HIP_MEMORY_SCOPE_AGENT);
      v.y = __hip_atomic_load(p + 1, __ATOMIC_RELAXED, __HIP_MEMORY_SCOPE_AGENT);
      a[kc] = __builtin_bit_cast(bf16x8, v);
    }

    // 4 independent chains: acc[g] over kc
    f32x4 acc[4] = {{0.f, 0.f, 0.f, 0.f},
                    {0.f, 0.f, 0.f, 0.f},
                    {0.f, 0.f, 0.f, 0.f},
                    {0.f, 0.f, 0.f, 0.f}};
#pragma unroll
    for (int kc = 0; kc < 4; ++kc)
#pragma unroll
      for (int g = 0; g < 4; ++g)
        acc[g] = __builtin_amdgcn_mfma_f32_16x16x32_bf16(a[kc], bfr[g][kc], acc[g], 0, 0, 0);

    {
      int crow = (lane >> 4) * 4;  // C layout: col=lane&15, row=(lane>>4)*4+r
#pragma unroll
      for (int g = 0; g < 4; ++g)
#pragma unroll
        for (int r = 0; r < 4; ++r) xchg[wave][g][crow + r][lm] = acc[g][r];
    }
    __syncthreads();

    float h_new = 0.f;
    if (tid < 256) {
      float raw[4];
#pragma unroll
      for (int g = 0; g < 4; ++g) {
        float s = xchg[0][g][r_b][u];
#pragma unroll
        for (int w = 1; w < 8; ++w) s += xchg[w][g][r_b][u];
        raw[g] = s;
      }
      float ig = sigm(raw[0] + b2f(xr0));
      float fg = sigm(raw[1] + b2f(xr1));
      float gg = tanh_(raw[2] + b2f(xr2));
      float og = sigm(raw[3] + b2f(xr3));
      c_val = fg * c_val + ig * gg;
      h_new = og * tanh_(c_val);
      // paired u32 agent-scope store (write-through to coherence point)
      uint32_t mine = f2b(h_new);
      uint32_t other = __shfl_xor(mine, 1);
      if ((u & 1) == 0) {
        uint32_t pair = mine | (other << 16);
        __hip_atomic_store(
            (uint32_t*)(h_buf + (size_t)(t & 1) * 65536 + (size_t)b * 1024 + unit), pair,
            __ATOMIC_RELAXED, __HIP_MEMORY_SCOPE_AGENT);
      }
      if (t == 511) {
        out_hT[b * 1024 + unit] = h_new;
        out_cT[b * 1024 + unit] = c_val;
      }
    }

    if (ts != W - 1) {
      __syncthreads();  // drains vmcnt(0): h_buf stores globally visible
      uint32_t* fl = flags + ((size_t)t * 4 + bq) * 64;
      if (wave == 7) {
        if (lane == 0)
          __hip_atomic_store(fl + ub, 1u, __ATOMIC_RELAXED, __HIP_MEMORY_SCOPE_AGENT);
        uint32_t spin = 0;
        for (; spin < (1u << 15); ++spin) {  // bounded: never wedge
          uint32_t v = __hip_atomic_load(fl + lane, __ATOMIC_RELAXED,
                                         __HIP_MEMORY_SCOPE_AGENT);
          if (__all(v == 1u)) break;
          __builtin_amdgcn_s_sleep(1);
        }
        if (spin >= (1u << 15) && lane == 0)  // sentinel: absmax ~1e6
          out_h[(size_t)t * 65536 + bid] = 1.0e6f;
      }
      // out_h store overlaps the poll (not part of the inter-block protocol)
      if (tid < 256) out_h[(size_t)t * 65536 + (size_t)b * 1024 + unit] = h_new;
      __syncthreads();
    } else {
      if (tid < 256) out_h[(size_t)t * 65536 + (size_t)b * 1024 + unit] = h_new;
    }
  }

  if (tid < 256) c_st[b * 1024 + unit] = c_val;
}

// -------------------------------------------------------------------- launch
extern "C" void kernel_launch(void* const* d_in, const int* in_sizes, int n_in,
                              void* d_out, int out_size, void* d_ws, size_t ws_size,
                              hipStream_t stream) {
  const float* x = (const float*)d_in[0];
  const float* h0 = (const float*)d_in[1];
  const float* c0 = (const float*)d_in[2];
  const float* wih = (const float*)d_in[3];
  const float* whh = (const float*)d_in[4];
  const float* bias = (const float*)d_in[5];

  float* out = (float*)d_out;
  float* out_h = out;                              // [512][64][1024]
  float* out_hT = out + (size_t)512 * 64 * 1024;   // [64][1024]
  float* out_cT = out_hT + 64 * 1024;              // [64][1024]

  // adaptive xg window (bf16): W in {64,16,4}
  const size_t fixed = (size_t)2 * 4096 * 1024 * 2   // wih_t + whh_t
                       + (size_t)2 * 64 * 1024 * 2   // h_buf
                       + (size_t)64 * 1024 * 4       // c_state
                       + (size_t)512 * 4 * 64 * 4;   // flags
  int W = 64;
  while (W > 4 && fixed + (size_t)W * 64 * 4096 * 2 > ws_size) W >>= 2;

  char* ws = (char*)d_ws;
  u16* wih_t = (u16*)ws;   ws += (size_t)4096 * 1024 * 2;    // 8MB
  u16* whh_t = (u16*)ws;   ws += (size_t)4096 * 1024 * 2;    // 8MB
  u16* xg = (u16*)ws;      ws += (size_t)W * 64 * 4096 * 2;  // <=32MB
  u16* h_buf = (u16*)ws;   ws += (size_t)2 * 64 * 1024 * 2;  // 256KB
  float* c_st = (float*)ws; ws += (size_t)64 * 1024 * 4;     // 256KB
  uint32_t* flags = (uint32_t*)ws;                           // 512KB

  hipMemsetAsync(flags, 0, (size_t)512 * 4 * 64 * 4, stream);
  convert_h0<<<64, 256, 0, stream>>>(h0, h_buf + 65536);  // h_{-1} in buf 1
  hipMemcpyAsync(c_st, c0, (size_t)64 * 1024 * 4, hipMemcpyDeviceToDevice, stream);
  transpose_w<<<dim3(64, 16, 2), 256, 0, stream>>>(wih, whh, wih_t, whh_t);

  for (int t0 = 0; t0 < 512; t0 += W) {
    gemm_xg<<<dim3(32, W / 2), 256, 0, stream>>>(x + (size_t)t0 * 64 * 1024, wih_t, bias, xg);
    int t0c = t0, Wc = W;
    void* args[] = {(void*)&xg,    (void*)&whh_t,  (void*)&h_buf,  (void*)&c_st,
                    (void*)&out_h, (void*)&out_hT, (void*)&out_cT, (void*)&flags,
                    (void*)&t0c,   (void*)&Wc};
    hipLaunchCooperativeKernel((const void*)recur_pers, dim3(256), dim3(512), args, 0,
                               stream);
  }
}

// Round 11
// 4063.021 us; speedup vs baseline: 4.4252x; 1.0392x over previous
//
#include <hip/hip_runtime.h>
#include <stdint.h>

// R11: R10 protocol (PASS, 435us/win) + dual-stream latency hiding.
// LSTM rows are batch-independent => 4 bq-groups never interact. Each block
// now owns TWO group-streams (pair p = bid>>6 -> groups 2p, 2p+1) and
// alternates phases: while stream A's {h-store drain -> flag -> poll} latency
// resolves through L3, the block computes stream B's step. Flag-wait moved to
// phase TOP (polls hit flags set ~1.3us earlier => off critical path).
// Per-phase protocol byte-equivalent to R10: agent h store -> __syncthreads
// (vmcnt drain) -> flag store; consumer: poll -> sync -> agent h load.
// Grid 128 blocks; W_hh frags shared by both streams (64 VGPRs); one shared
// 32KB xchg (A's reads complete before A's drain; B writes after).

typedef unsigned short u16;
typedef __attribute__((ext_vector_type(8))) short bf16x8;
typedef __attribute__((ext_vector_type(2))) uint64_t u64x2;
typedef __attribute__((ext_vector_type(4))) float f32x4;

static __device__ __forceinline__ u16 f2b(float f) {
  uint32_t b = __float_as_uint(f);
  return (u16)((b + 0x7fffu + ((b >> 16) & 1u)) >> 16);  // RNE
}
static __device__ __forceinline__ uint64_t pack4(float4 v) {
  return (uint64_t)f2b(v.x) | ((uint64_t)f2b(v.y) << 16) |
         ((uint64_t)f2b(v.z) << 32) | ((uint64_t)f2b(v.w) << 48);
}
static __device__ __forceinline__ float b2f(u16 u) {
  return __uint_as_float(((uint32_t)u) << 16);
}
static __device__ __forceinline__ float sigm(float x) {
  return 1.0f / (1.0f + __expf(-x));
}
static __device__ __forceinline__ float tanh_(float x) {
  float e = __expf(2.0f * x);
  return 1.0f - 2.0f / (e + 1.0f);
}

// ---------------------------------------------------------------- prep kernels
__global__ __launch_bounds__(256) void transpose_w(const float* __restrict__ Wih,
                                                   const float* __restrict__ Whh,
                                                   u16* __restrict__ Tih,
                                                   u16* __restrict__ Thh) {
  __shared__ float tile[64][65];
  const float* src = blockIdx.z ? Whh : Wih;
  u16* dst = blockIdx.z ? Thh : Tih;
  int k0 = blockIdx.y * 64, n0 = blockIdx.x * 64;
  int tid = threadIdx.x;
#pragma unroll
  for (int i = 0; i < 16; ++i) {
    int idx = i * 256 + tid;
    int kl = idx >> 6, nl = idx & 63;
    tile[kl][nl] = src[(size_t)(k0 + kl) * 4096 + n0 + nl];
  }
  __syncthreads();
#pragma unroll
  for (int i = 0; i < 16; ++i) {
    int idx = i * 256 + tid;
    int nl = idx >> 6, kl = idx & 63;
    dst[(size_t)(n0 + nl) * 1024 + k0 + kl] = f2b(tile[kl][nl]);
  }
}

__global__ __launch_bounds__(256) void convert_h0(const float* __restrict__ h0,
                                                  u16* __restrict__ dst) {
  int i = blockIdx.x * 256 + threadIdx.x;  // 16384 float4s
  float4 v = ((const float4*)h0)[i];
  ((uint64_t*)dst)[i] = pack4(v);
}

// ------------------------------------------------------------------- big GEMM
// C[M][4096] bf16 = A[M][1024] f32 @ Bt[4096][1024]^T + bias. (unchanged, PASS)
__global__ __launch_bounds__(256) void gemm_xg(const float* __restrict__ A,
                                               const u16* __restrict__ Bt,
                                               const float* __restrict__ bias,
                                               u16* __restrict__ C) {
  __shared__ u16 sA[2][128 * 32];
  __shared__ u16 sB[2][128 * 32];
  const int tid = threadIdx.x;
  const int wave = tid >> 6, lane = tid & 63;
  const int bx = blockIdx.x, by = blockIdx.y;
  const int wr = wave >> 1, wc = wave & 1;
  const int lm = lane & 15, ko = (lane >> 4) * 8;

  const int ar = lane >> 1, ac = (lane & 1) * 16;
  const float* gA = A + (size_t)(by * 128 + wave * 32 + ar) * 1024 + ac;
  const u16* gB = Bt + (size_t)(bx * 128 + wave * 32 + (lane >> 2)) * 1024 + (lane & 3) * 8;
  const int bidx = wave * 1024 + (lane >> 2) * 32 + (lane & 3) * 8;

  f32x4 acc[4][4] = {};

  auto stage = [&](int kt, int buf) {
    const u16* gb = gB + kt * 32;
    bf16x8 b0 = *(const bf16x8*)gb;
    bf16x8 b1 = *(const bf16x8*)(gb + 16 * 1024);
    *(bf16x8*)&sB[buf][bidx] = b0;
    *(bf16x8*)&sB[buf][bidx + 512] = b1;
    const float* ga = gA + kt * 32;
    float4 v0 = *(const float4*)(ga + 0);
    float4 v1 = *(const float4*)(ga + 4);
    float4 v2 = *(const float4*)(ga + 8);
    float4 v3 = *(const float4*)(ga + 12);
    uint64_t* la = (uint64_t*)&sA[buf][wave * 1024 + ar * 32 + ac];
    la[0] = pack4(v0);
    la[1] = pack4(v1);
    la[2] = pack4(v2);
    la[3] = pack4(v3);
  };

  stage(0, 0);
  __syncthreads();
  int p = 0;
  for (int kt = 0; kt < 32; ++kt) {
    if (kt < 31) stage(kt + 1, p ^ 1);
    bf16x8 af[4], bfv[4];
#pragma unroll
    for (int i = 0; i < 4; ++i)
      af[i] = *(const bf16x8*)&sA[p][(wr * 64 + i * 16 + lm) * 32 + ko];
#pragma unroll
    for (int j = 0; j < 4; ++j)
      bfv[j] = *(const bf16x8*)&sB[p][(wc * 64 + j * 16 + lm) * 32 + ko];
#pragma unroll
    for (int i = 0; i < 4; ++i)
#pragma unroll
      for (int j = 0; j < 4; ++j)
        acc[i][j] = __builtin_amdgcn_mfma_f32_16x16x32_bf16(af[i], bfv[j], acc[i][j], 0, 0, 0);
    __syncthreads();
    p ^= 1;
  }

  float bj[4];
#pragma unroll
  for (int j = 0; j < 4; ++j)
    bj[j] = bias[bx * 128 + wc * 64 + j * 16 + lm];
#pragma unroll
  for (int i = 0; i < 4; ++i) {
    int row = by * 128 + wr * 64 + i * 16 + (lane >> 4) * 4;
#pragma unroll
    for (int j = 0; j < 4; ++j) {
      int col = bx * 128 + wc * 64 + j * 16 + lm;
#pragma unroll
      for (int r = 0; r < 4; ++r)
        C[(size_t)(row + r) * 4096 + col] = f2b(acc[i][j][r] + bj[j]);
    }
  }
}

// ------------------------------------- persistent dual-stream recurrence
// Grid 128 blocks, block 512 (8 waves). bid: ub=bid&63, pair=bid>>6.
// Streams: bq_A=pair*2, bq_B=pair*2+1 (16 batch rows each, fully independent).
// Wave w owns K-slice [w*128,+128) for all 4 gates (bfr[g][kc], 64 VGPRs,
// shared by both streams). Per phase: poll(t-1)@top -> sync -> agent h load
// -> 16 MFMA -> xchg -> sync -> reduce+cell -> h/out store -> drain -> flag(t).
__global__ __launch_bounds__(512, 1) void recur_pers(
    const u16* __restrict__ xg,      // [W][64][4096] bf16, bias already added
    const u16* __restrict__ whh_t,   // [4096][1024] bf16
    u16* __restrict__ h_buf,         // [2][64][1024] bf16 ping-pong
    float* __restrict__ c_st,        // [64][1024] f32
    float* __restrict__ out_h,       // [512][64][1024] f32
    float* __restrict__ out_hT, float* __restrict__ out_cT,
    uint32_t* __restrict__ flags,    // [512][4][64] u32, zeroed once
    int t0, int W) {
  __shared__ float xchg[8][4][16][16];  // 32KB, shared by both streams

  const int tid = threadIdx.x;
  const int wave = tid >> 6, lane = tid & 63;
  const int bid = blockIdx.x;
  const int ub = bid & 63;
  const int pair = bid >> 6;  // 0 or 1
  const int lm = lane & 15, ko = (lane >> 4) * 8;

  // W_hh B-frags resident: bfr[gate][kc], k = wave*128 + kc*32 + ko + j
  bf16x8 bfr[4][4];
#pragma unroll
  for (int g = 0; g < 4; ++g) {
    const u16* bp = whh_t + (size_t)(g * 1024 + ub * 16 + lm) * 1024 + wave * 128 + ko;
#pragma unroll
    for (int kc = 0; kc < 4; ++kc) bfr[g][kc] = *(const bf16x8*)(bp + kc * 32);
  }

  const int r_b = tid >> 4, u = tid & 15;
  const int unit = ub * 16 + u;
  const int bA = (pair * 2) * 16 + r_b;
  const int bB = (pair * 2 + 1) * 16 + r_b;
  float cA = (tid < 256) ? c_st[bA * 1024 + unit] : 0.f;
  float cB = (tid < 256) ? c_st[bB * 1024 + unit] : 0.f;

  auto phase = [&](int bq, float& c_val, int b, int ts, int t) {
    // ---- wait at top: previous step's flags (set ~1 phase ago => instant) ----
    if (t > 0) {
      uint32_t* fl = flags + ((size_t)(t - 1) * 4 + bq) * 64;
      if (wave == 7) {
        uint32_t spin = 0;
        for (; spin < (1u << 14); ++spin) {  // bounded: never wedge
          uint32_t v = __hip_atomic_load(fl + lane, __ATOMIC_RELAXED,
                                         __HIP_MEMORY_SCOPE_AGENT);
          if (__all(v == 1u)) break;
          __builtin_amdgcn_s_sleep(1);
        }
        if (spin >= (1u << 14) && lane == 0)  // sentinel: absmax ~1e6
          out_h[(size_t)t * 65536 + bid] = 1.0e6f;
      }
      __syncthreads();  // release all waves once poll confirms
    }

    // ---- xg prefetch (independent of h) ----
    u16 xr0 = 0, xr1 = 0, xr2 = 0, xr3 = 0;
    if (tid < 256) {
      const u16* xgp = xg + ((size_t)ts * 64 + b) * 4096 + unit;
      xr0 = xgp[0];
      xr1 = xgp[1024];
      xr2 = xgp[2048];
      xr3 = xgp[3072];
    }

    // ---- A-frags: 4 x 16B per lane, agent-scope (L3 coherence point) ----
    const u16* ap = h_buf + (size_t)((t - 1) & 1) * 65536 +
                    (size_t)(bq * 16 + lm) * 1024 + wave * 128 + ko;
    bf16x8 a[4];
#pragma unroll
    for (int kc = 0; kc < 4; ++kc) {
      const uint64_t* p = (const uint64_t*)(ap + kc * 32);
      u64x2 v;
      v.x = __hip_atomic_load(p, __ATOMIC_RELAXED, __HIP_MEMORY_SCOPE_AGENT);
      v.y = __hip_atomic_load(p + 1, __ATOMIC_RELAXED, __HIP_MEMORY_SCOPE_AGENT);
      a[kc] = __builtin_bit_cast(bf16x8, v);
    }

    f32x4 acc[4] = {{0.f, 0.f, 0.f, 0.f},
                    {0.f, 0.f, 0.f, 0.f},
                    {0.f, 0.f, 0.f, 0.f},
                    {0.f, 0.f, 0.f, 0.f}};
#pragma unroll
    for (int kc = 0; kc < 4; ++kc)
#pragma unroll
      for (int g = 0; g < 4; ++g)
        acc[g] = __builtin_amdgcn_mfma_f32_16x16x32_bf16(a[kc], bfr[g][kc], acc[g], 0, 0, 0);

    {
      int crow = (lane >> 4) * 4;  // C layout: col=lane&15, row=(lane>>4)*4+r
#pragma unroll
      for (int g = 0; g < 4; ++g)
#pragma unroll
        for (int r = 0; r < 4; ++r) xchg[wave][g][crow + r][lm] = acc[g][r];
    }
    __syncthreads();

    if (tid < 256) {
      float raw[4];
#pragma unroll
      for (int g = 0; g < 4; ++g) {
        float s = xchg[0][g][r_b][u];
#pragma unroll
        for (int w = 1; w < 8; ++w) s += xchg[w][g][r_b][u];
        raw[g] = s;
      }
      float ig = sigm(raw[0] + b2f(xr0));
      float fg = sigm(raw[1] + b2f(xr1));
      float gg = tanh_(raw[2] + b2f(xr2));
      float og = sigm(raw[3] + b2f(xr3));
      c_val = fg * c_val + ig * gg;
      float h_new = og * tanh_(c_val);
      uint32_t mine = f2b(h_new);
      uint32_t other = __shfl_xor(mine, 1);
      if ((u & 1) == 0) {
        uint32_t pairv = mine | (other << 16);
        __hip_atomic_store(
            (uint32_t*)(h_buf + (size_t)(t & 1) * 65536 + (size_t)b * 1024 + unit), pairv,
            __ATOMIC_RELAXED, __HIP_MEMORY_SCOPE_AGENT);
      }
      out_h[(size_t)t * 65536 + (size_t)b * 1024 + unit] = h_new;
      if (t == 511) {
        out_hT[b * 1024 + unit] = h_new;
        out_cT[b * 1024 + unit] = c_val;
      }
    }

    __syncthreads();  // vmcnt drain: h_buf stores globally visible
    if (wave == 7 && lane == 0)
      __hip_atomic_store(flags + ((size_t)t * 4 + bq) * 64 + ub, 1u, __ATOMIC_RELAXED,
                         __HIP_MEMORY_SCOPE_AGENT);
    // flag visibility latency hides under the other stream's phase
  };

  for (int ts = 0; ts < W; ++ts) {
    const int t = t0 + ts;
    phase(pair * 2, cA, bA, ts, t);
    phase(pair * 2 + 1, cB, bB, ts, t);
  }

  if (tid < 256) {
    c_st[bA * 1024 + unit] = cA;
    c_st[bB * 1024 + unit] = cB;
  }
}

// -------------------------------------------------------------------- launch
extern "C" void kernel_launch(void* const* d_in, const int* in_sizes, int n_in,
                              void* d_out, int out_size, void* d_ws, size_t ws_size,
                              hipStream_t stream) {
  const float* x = (const float*)d_in[0];
  const float* h0 = (const float*)d_in[1];
  const float* c0 = (const float*)d_in[2];
  const float* wih = (const float*)d_in[3];
  const float* whh = (const float*)d_in[4];
  const float* bias = (const float*)d_in[5];

  float* out = (float*)d_out;
  float* out_h = out;                              // [512][64][1024]
  float* out_hT = out + (size_t)512 * 64 * 1024;   // [64][1024]
  float* out_cT = out_hT + 64 * 1024;              // [64][1024]

  // adaptive xg window (bf16): W in {64,16,4}
  const size_t fixed = (size_t)2 * 4096 * 1024 * 2   // wih_t + whh_t
                       + (size_t)2 * 64 * 1024 * 2   // h_buf
                       + (size_t)64 * 1024 * 4       // c_state
                       + (size_t)512 * 4 * 64 * 4;   // flags
  int W = 64;
  while (W > 4 && fixed + (size_t)W * 64 * 4096 * 2 > ws_size) W >>= 2;

  char* ws = (char*)d_ws;
  u16* wih_t = (u16*)ws;   ws += (size_t)4096 * 1024 * 2;    // 8MB
  u16* whh_t = (u16*)ws;   ws += (size_t)4096 * 1024 * 2;    // 8MB
  u16* xg = (u16*)ws;      ws += (size_t)W * 64 * 4096 * 2;  // <=32MB
  u16* h_buf = (u16*)ws;   ws += (size_t)2 * 64 * 1024 * 2;  // 256KB
  float* c_st = (float*)ws; ws += (size_t)64 * 1024 * 4;     // 256KB
  uint32_t* flags = (uint32_t*)ws;                           // 512KB

  hipMemsetAsync(flags, 0, (size_t)512 * 4 * 64 * 4, stream);
  convert_h0<<<64, 256, 0, stream>>>(h0, h_buf + 65536);  // h_{-1} in buf 1
  hipMemcpyAsync(c_st, c0, (size_t)64 * 1024 * 4, hipMemcpyDeviceToDevice, stream);
  transpose_w<<<dim3(64, 16, 2), 256, 0, stream>>>(wih, whh, wih_t, whh_t);

  for (int t0 = 0; t0 < 512; t0 += W) {
    gemm_xg<<<dim3(32, W / 2), 256, 0, stream>>>(x + (size_t)t0 * 64 * 1024, wih_t, bias, xg);
    int t0c = t0, Wc = W;
    void* args[] = {(void*)&xg,    (void*)&whh_t,  (void*)&h_buf,  (void*)&c_st,
                    (void*)&out_h, (void*)&out_hT, (void*)&out_cT, (void*)&flags,
                    (void*)&t0c,   (void*)&Wc};
    hipLaunchCooperativeKernel((const void*)recur_pers, dim3(128), dim3(512), args, 0,
                               stream);
  }
}